// Round 4
// baseline (1885.909 us; speedup 1.0000x reference)
//
#include <hip/hip_runtime.h>

// ---------------------------------------------------------------------------
// Attention_4956392259713 — round 11: R9 core + 2-deep LDS => 2 blocks/CU.
// qkv = x@W^T+b; S = q@k^T (unscaled); P = softmax(S); out = P@v
//
// R8 (fine,no-swz)=75us, R9 (coarse+swz)=66us, R10 (fine+swz)=74.5us: all at
// 1 block/CU (128KB LDS), MfmaUtil ~30%. Cycle model: MFMA ~1240 + LDS ~1150
// cyc/K-tile vs ~3300 measured -> per-wave latency bubbles that 2 waves/SIMD
// can't hide. Untried axis: occupancy (m114 cross-block overlap; m97's 912TF
// ran ~3 blocks/CU with a naive loop). Round 11 = R9 body verbatim (1 barrier
// per K-tile, no lgkm drains, 0-conflict swizzle) with:
//   - 2-deep LDS double-buffer: 2 x (As 16KB + Bs 16KB) = 64KB -> 2 blocks/CU
//   - __launch_bounds__(512,4): 16 waves/CU, VGPR cap 128 (R9 measured 100)
//   - stage(t+1) issued at TOP of iter t (load lead ~ full iter >> HBM lat),
//     drained by vmcnt(0) after the MFMA cluster; co-resident block hides any
//     residual stall (cross-block overlap = the new latency-hiding mechanism)
// Swizzle (64B rows, verified 0 conflicts in R9/R10): 16B-unit U=u^((row>>1)&3);
// write side = linear gld16 dest + pre-swizzled GLOBAL column (rule #21);
// read side folded into per-lane constant ku.
// Numerics identical (fp16 QKV/QK^T; bf16 E and PV; no max subtraction).
// Fragment maps (m89-verified): A/B idx=lane&15, k=(lane>>4)*8+j;
//                               C/D col=lane&15, row=(lane>>4)*4+reg.
// ---------------------------------------------------------------------------

typedef short    s16x8 __attribute__((ext_vector_type(8)));
typedef _Float16 h16x8 __attribute__((ext_vector_type(8)));
typedef _Float16 h16x4 __attribute__((ext_vector_type(4)));
typedef float    f32x4 __attribute__((ext_vector_type(4)));

__device__ __forceinline__ unsigned short f2bf(float x) {
    unsigned u = __float_as_uint(x);
    u += 0x7fffu + ((u >> 16) & 1u);          // RTNE
    return (unsigned short)(u >> 16);
}
__device__ __forceinline__ float bf2f(unsigned short h) {
    return __uint_as_float(((unsigned)h) << 16);
}
__device__ __forceinline__ unsigned short f2h(float x) {
    _Float16 h = (_Float16)x;                 // v_cvt_f16_f32, RTNE
    unsigned short u;
    __builtin_memcpy(&u, &h, 2);
    return u;
}
__device__ __forceinline__ h16x8 as_h(s16x8 v) {
    h16x8 r; __builtin_memcpy(&r, &v, 16); return r;
}

// async global->LDS, 16 B per lane; LDS dest = wave-uniform base + lane*16
__device__ __forceinline__ void gld16(const void* g, void* l) {
    __builtin_amdgcn_global_load_lds(
        (const __attribute__((address_space(1))) unsigned int*)(unsigned long long)g,
        (__attribute__((address_space(3))) unsigned int*)(unsigned)(unsigned long long)l,
        16, 0, 0);
}

template<bool FP16>
__device__ __forceinline__ f32x4 mma(s16x8 a, s16x8 b, f32x4 c) {
    if constexpr (FP16)
        return __builtin_amdgcn_mfma_f32_16x16x32_f16(as_h(a), as_h(b), c, 0, 0, 0);
    else
        return __builtin_amdgcn_mfma_f32_16x16x32_bf16(a, b, c, 0, 0, 0);
}

// NT GEMM, 512 thr = 8 waves (2Mx4N), tile 256x256, BK=32, 2-deep dbuf.
// MODE 1: C = acc + bias -> fp16        [K1a]
// MODE 2: C = acc + bias -> bf16        [K1b]
// MODE 3: C = exp(acc)   -> bf16        [K2]
// MODE 4: C = acc * rvec[row] -> f32    [K4]
// SWZ 0: none; 1: 3D batch-per-XCD; 2: 2D row-chunk-per-XCD (gridDim.y%8==0)
template<int MODE, bool FP16, int SWZ>
__global__ __launch_bounds__(512, 4)
void gemm_mfma(const unsigned short* __restrict__ A, const unsigned short* __restrict__ B,
               const float* __restrict__ bias, const float* __restrict__ rvec,
               float* __restrict__ Cf, unsigned short* __restrict__ Ch,
               int K, int lda, int ldb, int ldc,
               long long sA, long long sB, long long sC, long long sR)
{
    __shared__ unsigned short As[2][8192];    // 2 x [256 rows][32 k] 2B, swizzled
    __shared__ unsigned short Bs[2][8192];

    int bx = blockIdx.x, by = blockIdx.y, bz = blockIdx.z;
    if (SWZ == 1) {
        const int l = bx + gridDim.x * (by + gridDim.y * bz);
        bz = l & 7;
        const int t = l >> 3;
        bx = t % gridDim.x;
        by = t / gridDim.x;
    } else if (SWZ == 2) {
        const int l = bx + gridDim.x * by;
        const int c = l & 7;
        const int t = l >> 3;
        const int rows = gridDim.y >> 3;
        bx = t % gridDim.x;
        by = c * rows + t / gridDim.x;
    }

    A += (long long)bz * sA;
    B += (long long)bz * sB;

    const long long m0 = (long long)by * 256;
    const long long n0 = (long long)bx * 256;

    const int tid  = threadIdx.x;
    const int wave = tid >> 6, lane = tid & 63;
    const int wr = wave >> 2, wc = wave & 3;             // 2M x 4N wave grid
    const int ml = lane & 15;                            // fragment row-in-16
    // swizzled k-unit for fragment reads: U = u ^ ((row>>1)&3); row bases are
    // multiples of 16 so (row>>1)&3 == (ml>>1)&3 -> per-lane constant.
    const int ku = (((lane >> 4) ^ ((ml >> 1) & 3)) * 8);
    const int srr = wave * 16 + (lane >> 2);             // staging row 0..127
    // pre-swizzled GLOBAL column: slot (r,U) holds global unit u = U^((r>>1)&3),
    // with r = wave*16 + (lane>>2) -> (r>>1)&3 == (lane>>3)&3.
    const int skc = (((lane & 3) ^ ((lane >> 3) & 3)) * 8);

    const int aidx = (wr * 128 + ml) * 32 + ku;          // LDS elem index
    const int bidx = (wc * 64  + ml) * 32 + ku;

    const unsigned short* Abase = A + (m0 + srr) * (long long)lda + skc;
    const unsigned short* Bbase = B + (n0 + srr) * (long long)ldb + skc;
    const long long a128 = 128LL * lda, b128 = 128LL * ldb;

    // stage one 256x32 operand tile: 2 x (512 thr x 16B) = 16KB
    auto stage_a = [&](int t, int buf) {
        const unsigned short* p = Abase + t * 32;
        gld16(p,        &As[buf][wave * 512]);
        gld16(p + a128, &As[buf][4096 + wave * 512]);
    };
    auto stage_b = [&](int t, int buf) {
        const unsigned short* p = Bbase + t * 32;
        gld16(p,        &Bs[buf][wave * 512]);
        gld16(p + b128, &Bs[buf][4096 + wave * 512]);
    };

    f32x4 acc[8][4];
#pragma unroll
    for (int i = 0; i < 8; ++i)
#pragma unroll
        for (int j = 0; j < 4; ++j) acc[i][j] = f32x4{0.f, 0.f, 0.f, 0.f};

    const int nt = K >> 5;                    // K-tiles of 32

    // prologue: stage tile 0 into buf 0
    stage_a(0, 0); stage_b(0, 0);
    asm volatile("s_waitcnt vmcnt(0)" ::: "memory");
    __builtin_amdgcn_s_barrier();
    __builtin_amdgcn_sched_barrier(0);

    for (int t = 0; t < nt; ++t) {
        const int cur = t & 1, nb = cur ^ 1;
        const unsigned short* as = &As[cur][0];
        const unsigned short* bs = &Bs[cur][0];
        const bool pf = (t + 1 < nt);

        // prefetch tile t+1 FIRST (max load lead time; buf nb fully consumed
        // by end of prev iter, so WAR-safe)
        if (pf) { stage_a(t + 1, nb); stage_b(t + 1, nb); }

        s16x8 a8[8], b4[4];
        // issue all 12 ds_reads; compiler emits granular lgkm waits so the
        // MFMA cluster below overlaps the tail reads.
#pragma unroll
        for (int i = 0; i < 4; ++i) a8[i] = *(const s16x8*)&as[aidx + i * 512];
#pragma unroll
        for (int j = 0; j < 4; ++j) b4[j] = *(const s16x8*)&bs[bidx + j * 512];
#pragma unroll
        for (int i = 0; i < 4; ++i) a8[4 + i] = *(const s16x8*)&as[aidx + (i + 4) * 512];

        __builtin_amdgcn_s_setprio(1);
#pragma unroll
        for (int i = 0; i < 8; ++i)
#pragma unroll
            for (int j = 0; j < 4; ++j)
                acc[i][j] = mma<FP16>(a8[i], b4[j], acc[i][j]);
        __builtin_amdgcn_s_setprio(0);

        // drain tile t+1 loads (issued ~a full iter ago -> usually complete)
        if (pf) { asm volatile("s_waitcnt vmcnt(0)" ::: "memory"); }
        __builtin_amdgcn_s_barrier();
        __builtin_amdgcn_sched_barrier(0);
    }

    // ---- epilogue: C/D map col=lane&15, row=(lane>>4)*4+reg
    const int r0 = (lane >> 4) * 4;
    const long long rowbase = m0 + wr * 128 + r0;
    const long long colbase = n0 + wc * 64 + ml;
    if (MODE == 1 || MODE == 2) {
#pragma unroll
        for (int i = 0; i < 8; ++i) {
            const long long rowb = rowbase + i * 16;
#pragma unroll
            for (int j = 0; j < 4; ++j) {
                const long long col = colbase + j * 16;
                const float bj = bias[col];
#pragma unroll
                for (int q = 0; q < 4; ++q) {
                    const float vv = acc[i][j][q] + bj;
                    Ch[(rowb + q) * (long long)ldc + col] = (MODE == 1) ? f2h(vv) : f2bf(vv);
                }
            }
        }
    } else if (MODE == 3) {
        Ch += (long long)bz * sC;
#pragma unroll
        for (int i = 0; i < 8; ++i) {
            const long long rowb = rowbase + i * 16;
#pragma unroll
            for (int j = 0; j < 4; ++j) {
                const long long col = colbase + j * 16;
#pragma unroll
                for (int q = 0; q < 4; ++q)
                    Ch[(rowb + q) * (long long)ldc + col] = f2bf(__expf(acc[i][j][q]));
            }
        }
    } else {   // MODE 4
        Cf += (long long)bz * sC;
        rvec += (long long)bz * sR;
#pragma unroll
        for (int i = 0; i < 8; ++i) {
            const long long rowb = rowbase + i * 16;
#pragma unroll
            for (int j = 0; j < 4; ++j) {
                const long long col = colbase + j * 16;
#pragma unroll
                for (int q = 0; q < 4; ++q)
                    Cf[(rowb + q) * (long long)ldc + col] = acc[i][j][q] * rvec[rowb + q];
            }
        }
    }
}

// f32 -> fp16 convert, 4 elems/thread
__global__ __launch_bounds__(256)
void cvt_f16(const float* __restrict__ in, unsigned short* __restrict__ out, long long n4)
{
    const long long i = (long long)blockIdx.x * 256 + threadIdx.x;
    if (i >= n4) return;
    const float4 v = ((const float4*)in)[i];
    h16x4 o;
    o.x = (_Float16)v.x; o.y = (_Float16)v.y;
    o.z = (_Float16)v.z; o.w = (_Float16)v.w;
    ((h16x4*)out)[i] = o;
}

// vt[b][h][n] = v[b*2048+n][h]   (V transpose, bf16)
__global__ __launch_bounds__(256)
void transpose_v(const unsigned short* __restrict__ v, unsigned short* __restrict__ vt)
{
    __shared__ unsigned short t[32][33];
    const int b = blockIdx.z;
    const int n0 = blockIdx.x * 32, h0 = blockIdx.y * 32;
    const int tx = threadIdx.x, ty = threadIdx.y;      // 32 x 8
    const unsigned short* src = v + (long long)b * 2048 * 768;
#pragma unroll
    for (int q = 0; q < 4; ++q)
        t[ty + q * 8][tx] = src[(long long)(n0 + ty + q * 8) * 768 + h0 + tx];
    __syncthreads();
    unsigned short* dst = vt + ((long long)b * 768 + h0) * 2048 + n0;
#pragma unroll
    for (int q = 0; q < 4; ++q)
        dst[(long long)(ty + q * 8) * 2048 + tx] = t[tx][ty + q * 8];
}

// r[row] = 1 / sum(E[row][0:2048])   (E bf16, one 256-thr block per row)
__global__ __launch_bounds__(256)
void rowsum_recip(const unsigned short* __restrict__ E, float* __restrict__ r)
{
    const long long row = blockIdx.x;
    const int t = threadIdx.x, lane = t & 63, w = t >> 6;
    __shared__ float red[4];
    const uint4 v = ((const uint4*)(E + row * 2048))[t];   // 8 bf16
    float s = bf2f((unsigned short)(v.x & 0xffff)) + bf2f((unsigned short)(v.x >> 16))
            + bf2f((unsigned short)(v.y & 0xffff)) + bf2f((unsigned short)(v.y >> 16))
            + bf2f((unsigned short)(v.z & 0xffff)) + bf2f((unsigned short)(v.z >> 16))
            + bf2f((unsigned short)(v.w & 0xffff)) + bf2f((unsigned short)(v.w >> 16));
#pragma unroll
    for (int o = 32; o; o >>= 1) s += __shfl_xor(s, o);
    if (lane == 0) red[w] = s;
    __syncthreads();
    if (t == 0) r[row] = 1.f / ((red[0] + red[1]) + (red[2] + red[3]));
}

extern "C" void kernel_launch(void* const* d_in, const int* in_sizes, int n_in,
                              void* d_out, int out_size, void* d_ws, size_t ws_size,
                              hipStream_t stream)
{
    const float* x    = (const float*)d_in[0];   // [16384, 768]
    const float* W    = (const float*)d_in[1];   // [2304, 768]
    const float* bias = (const float*)d_in[2];   // [2304]
    float* out = (float*)d_out;                  // [8, 2048, 768]

    // ---- workspace layout (bytes), total 196.5 MB
    char* ws = (char*)d_ws;
    unsigned short* xh = (unsigned short*)ws;                      // [16384,768] fp16
    unsigned short* Wh = (unsigned short*)(ws + 25165824LL);       // [2304,768] fp16
    unsigned short* qk = (unsigned short*)(ws + 28704768LL);       // [16384,1536] fp16
    unsigned short* v  = (unsigned short*)(ws + 79036416LL);       // [16384,768] bf16
    unsigned short* vt = (unsigned short*)(ws + 104202240LL);      // [8,768,2048] bf16
    unsigned short* E  = (unsigned short*)(ws + 129368064LL);      // [8,2048,2048] bf16
    float*          r  = (float*)(ws + 196476928LL);               // [16384] f32

    // C1/C2: convert inputs to fp16
    cvt_f16<<<dim3(12288), dim3(256), 0, stream>>>(x, xh, 3145728LL);
    cvt_f16<<<dim3(1728),  dim3(256), 0, stream>>>(W, Wh, 442368LL);

    // K1a: qk = x @ Wqk^T + b  (fp16, M=16384 N=1536 K=768), 2D chunk swizzle
    gemm_mfma<1, true, 2><<<dim3(6, 64, 1), dim3(512), 0, stream>>>(
        xh, Wh, bias, nullptr, nullptr, qk,
        768, 768, 768, 1536, 0, 0, 0, 0);

    // K1b: v = x @ Wv^T + b -> bf16  (M=16384 N=768 K=768), 2D chunk swizzle
    gemm_mfma<2, true, 2><<<dim3(3, 64, 1), dim3(512), 0, stream>>>(
        xh, Wh + 1536LL * 768, bias + 1536, nullptr, nullptr, v,
        768, 768, 768, 768, 0, 0, 0, 0);

    // T: vt = v^T per batch
    transpose_v<<<dim3(64, 24, 8), dim3(32, 8), 0, stream>>>(v, vt);

    // K2: E = exp(q @ k^T)  (fp16, M=2048 N=2048 K=768, z=8), batch-per-XCD
    gemm_mfma<3, true, 1><<<dim3(8, 8, 8), dim3(512), 0, stream>>>(
        qk, qk + 768, nullptr, nullptr, nullptr, E,
        768, 1536, 1536, 2048,
        2048LL * 1536, 2048LL * 1536, 2048LL * 2048, 0);

    // K3': r = 1/rowsum(E)
    rowsum_recip<<<dim3(16384), dim3(256), 0, stream>>>(E, r);

    // K4: out = (E @ vt^T) * r[row]  (bf16, M=2048 N=768 K=2048, z=8), batch-per-XCD
    gemm_mfma<4, false, 1><<<dim3(3, 8, 8), dim3(512), 0, stream>>>(
        E, vt, nullptr, r, out, nullptr,
        2048, 2048, 2048, 768,
        2048LL * 2048, 768LL * 2048, 2048LL * 768, 2048);
}

// Round 5
// 337.310 us; speedup vs baseline: 5.5910x; 5.5910x over previous
//
#include <hip/hip_runtime.h>

// ---------------------------------------------------------------------------
// Attention_4956392259713 — round 12: R11 retry with correct register budget.
// qkv = x@W^T+b; S = q@k^T (unscaled); P = softmax(S); out = P@v
//
// R11 post-mortem: __launch_bounds__(512,4) capped VGPR at 128 < 100 state
// + 128 acc -> allocator spilled acc to scratch (VGPR_Count=64, WRITE_SIZE
// 1.63GB/dispatch, MfmaUtil 3%, 637us). The occupancy hypothesis was never
// tested. Round 12 = identical body, __launch_bounds__(512,2) (cap 256, R9
// measured 100 VGPR -> no spill) + 64KB LDS kept:
//   occupancy = min(LDS: 160/64 = 2 blocks, VGPR@~116: 4 waves/SIMD = 2
//   blocks) = 2 blocks/CU = 16 waves/CU — double R9's.
// Core = R9's proven loop (K2 66us, 0 bank conflicts): single s_barrier per
// K-tile, no manual lgkm drains (compiler emits granular waits -> MFMAs
// overlap tail ds_reads), stage(t+1) at top of iter t, vmcnt(0) drain after
// the MFMA cluster, cross-block overlap hides the residual stall (m114).
// Swizzle (64B rows, verified 0 conflicts): 16B-unit U=u^((row>>1)&3);
// write side = linear gld16 dest + pre-swizzled GLOBAL column (rule #21);
// read side folded into per-lane constant ku.
// Numerics identical (fp16 QKV/QK^T; bf16 E and PV; no max subtraction).
// Fragment maps (m89-verified): A/B idx=lane&15, k=(lane>>4)*8+j;
//                               C/D col=lane&15, row=(lane>>4)*4+reg.
// ---------------------------------------------------------------------------

typedef short    s16x8 __attribute__((ext_vector_type(8)));
typedef _Float16 h16x8 __attribute__((ext_vector_type(8)));
typedef _Float16 h16x4 __attribute__((ext_vector_type(4)));
typedef float    f32x4 __attribute__((ext_vector_type(4)));

__device__ __forceinline__ unsigned short f2bf(float x) {
    unsigned u = __float_as_uint(x);
    u += 0x7fffu + ((u >> 16) & 1u);          // RTNE
    return (unsigned short)(u >> 16);
}
__device__ __forceinline__ float bf2f(unsigned short h) {
    return __uint_as_float(((unsigned)h) << 16);
}
__device__ __forceinline__ unsigned short f2h(float x) {
    _Float16 h = (_Float16)x;                 // v_cvt_f16_f32, RTNE
    unsigned short u;
    __builtin_memcpy(&u, &h, 2);
    return u;
}
__device__ __forceinline__ h16x8 as_h(s16x8 v) {
    h16x8 r; __builtin_memcpy(&r, &v, 16); return r;
}

// async global->LDS, 16 B per lane; LDS dest = wave-uniform base + lane*16
__device__ __forceinline__ void gld16(const void* g, void* l) {
    __builtin_amdgcn_global_load_lds(
        (const __attribute__((address_space(1))) unsigned int*)(unsigned long long)g,
        (__attribute__((address_space(3))) unsigned int*)(unsigned)(unsigned long long)l,
        16, 0, 0);
}

template<bool FP16>
__device__ __forceinline__ f32x4 mma(s16x8 a, s16x8 b, f32x4 c) {
    if constexpr (FP16)
        return __builtin_amdgcn_mfma_f32_16x16x32_f16(as_h(a), as_h(b), c, 0, 0, 0);
    else
        return __builtin_amdgcn_mfma_f32_16x16x32_bf16(a, b, c, 0, 0, 0);
}

// NT GEMM, 512 thr = 8 waves (2Mx4N), tile 256x256, BK=32, 2-deep dbuf.
// MODE 1: C = acc + bias -> fp16        [K1a]
// MODE 2: C = acc + bias -> bf16        [K1b]
// MODE 3: C = exp(acc)   -> bf16        [K2]
// MODE 4: C = acc * rvec[row] -> f32    [K4]
// SWZ 0: none; 1: 3D batch-per-XCD; 2: 2D row-chunk-per-XCD (gridDim.y%8==0)
template<int MODE, bool FP16, int SWZ>
__global__ __launch_bounds__(512, 2)
void gemm_mfma(const unsigned short* __restrict__ A, const unsigned short* __restrict__ B,
               const float* __restrict__ bias, const float* __restrict__ rvec,
               float* __restrict__ Cf, unsigned short* __restrict__ Ch,
               int K, int lda, int ldb, int ldc,
               long long sA, long long sB, long long sC, long long sR)
{
    __shared__ unsigned short As[2][8192];    // 2 x [256 rows][32 k] 2B, swizzled
    __shared__ unsigned short Bs[2][8192];

    int bx = blockIdx.x, by = blockIdx.y, bz = blockIdx.z;
    if (SWZ == 1) {
        const int l = bx + gridDim.x * (by + gridDim.y * bz);
        bz = l & 7;
        const int t = l >> 3;
        bx = t % gridDim.x;
        by = t / gridDim.x;
    } else if (SWZ == 2) {
        const int l = bx + gridDim.x * by;
        const int c = l & 7;
        const int t = l >> 3;
        const int rows = gridDim.y >> 3;
        bx = t % gridDim.x;
        by = c * rows + t / gridDim.x;
    }

    A += (long long)bz * sA;
    B += (long long)bz * sB;

    const long long m0 = (long long)by * 256;
    const long long n0 = (long long)bx * 256;

    const int tid  = threadIdx.x;
    const int wave = tid >> 6, lane = tid & 63;
    const int wr = wave >> 2, wc = wave & 3;             // 2M x 4N wave grid
    const int ml = lane & 15;                            // fragment row-in-16
    // swizzled k-unit for fragment reads: U = u ^ ((row>>1)&3); row bases are
    // multiples of 16 so (row>>1)&3 == (ml>>1)&3 -> per-lane constant.
    const int ku = (((lane >> 4) ^ ((ml >> 1) & 3)) * 8);
    const int srr = wave * 16 + (lane >> 2);             // staging row 0..127
    // pre-swizzled GLOBAL column: slot (r,U) holds global unit u = U^((r>>1)&3),
    // with r = wave*16 + (lane>>2) -> (r>>1)&3 == (lane>>3)&3.
    const int skc = (((lane & 3) ^ ((lane >> 3) & 3)) * 8);

    const int aidx = (wr * 128 + ml) * 32 + ku;          // LDS elem index
    const int bidx = (wc * 64  + ml) * 32 + ku;

    const unsigned short* Abase = A + (m0 + srr) * (long long)lda + skc;
    const unsigned short* Bbase = B + (n0 + srr) * (long long)ldb + skc;
    const long long a128 = 128LL * lda, b128 = 128LL * ldb;

    // stage one 256x32 operand tile: 2 x (512 thr x 16B) = 16KB
    auto stage_a = [&](int t, int buf) {
        const unsigned short* p = Abase + t * 32;
        gld16(p,        &As[buf][wave * 512]);
        gld16(p + a128, &As[buf][4096 + wave * 512]);
    };
    auto stage_b = [&](int t, int buf) {
        const unsigned short* p = Bbase + t * 32;
        gld16(p,        &Bs[buf][wave * 512]);
        gld16(p + b128, &Bs[buf][4096 + wave * 512]);
    };

    f32x4 acc[8][4];
#pragma unroll
    for (int i = 0; i < 8; ++i)
#pragma unroll
        for (int j = 0; j < 4; ++j) acc[i][j] = f32x4{0.f, 0.f, 0.f, 0.f};

    const int nt = K >> 5;                    // K-tiles of 32

    // prologue: stage tile 0 into buf 0
    stage_a(0, 0); stage_b(0, 0);
    asm volatile("s_waitcnt vmcnt(0)" ::: "memory");
    __builtin_amdgcn_s_barrier();
    __builtin_amdgcn_sched_barrier(0);

    for (int t = 0; t < nt; ++t) {
        const int cur = t & 1, nb = cur ^ 1;
        const unsigned short* as = &As[cur][0];
        const unsigned short* bs = &Bs[cur][0];
        const bool pf = (t + 1 < nt);

        // prefetch tile t+1 FIRST (max load lead time; buf nb fully consumed
        // by end of prev iter, so WAR-safe)
        if (pf) { stage_a(t + 1, nb); stage_b(t + 1, nb); }

        s16x8 a8[8], b4[4];
        // issue all 12 ds_reads; compiler emits granular lgkm waits so the
        // MFMA cluster below overlaps the tail reads.
#pragma unroll
        for (int i = 0; i < 4; ++i) a8[i] = *(const s16x8*)&as[aidx + i * 512];
#pragma unroll
        for (int j = 0; j < 4; ++j) b4[j] = *(const s16x8*)&bs[bidx + j * 512];
#pragma unroll
        for (int i = 0; i < 4; ++i) a8[4 + i] = *(const s16x8*)&as[aidx + (i + 4) * 512];

        __builtin_amdgcn_s_setprio(1);
#pragma unroll
        for (int i = 0; i < 8; ++i)
#pragma unroll
            for (int j = 0; j < 4; ++j)
                acc[i][j] = mma<FP16>(a8[i], b4[j], acc[i][j]);
        __builtin_amdgcn_s_setprio(0);

        // drain tile t+1 loads (issued ~a full iter ago -> usually complete)
        if (pf) { asm volatile("s_waitcnt vmcnt(0)" ::: "memory"); }
        __builtin_amdgcn_s_barrier();
        __builtin_amdgcn_sched_barrier(0);
    }

    // ---- epilogue: C/D map col=lane&15, row=(lane>>4)*4+reg
    const int r0 = (lane >> 4) * 4;
    const long long rowbase = m0 + wr * 128 + r0;
    const long long colbase = n0 + wc * 64 + ml;
    if (MODE == 1 || MODE == 2) {
#pragma unroll
        for (int i = 0; i < 8; ++i) {
            const long long rowb = rowbase + i * 16;
#pragma unroll
            for (int j = 0; j < 4; ++j) {
                const long long col = colbase + j * 16;
                const float bj = bias[col];
#pragma unroll
                for (int q = 0; q < 4; ++q) {
                    const float vv = acc[i][j][q] + bj;
                    Ch[(rowb + q) * (long long)ldc + col] = (MODE == 1) ? f2h(vv) : f2bf(vv);
                }
            }
        }
    } else if (MODE == 3) {
        Ch += (long long)bz * sC;
#pragma unroll
        for (int i = 0; i < 8; ++i) {
            const long long rowb = rowbase + i * 16;
#pragma unroll
            for (int j = 0; j < 4; ++j) {
                const long long col = colbase + j * 16;
#pragma unroll
                for (int q = 0; q < 4; ++q)
                    Ch[(rowb + q) * (long long)ldc + col] = f2bf(__expf(acc[i][j][q]));
            }
        }
    } else {   // MODE 4
        Cf += (long long)bz * sC;
        rvec += (long long)bz * sR;
#pragma unroll
        for (int i = 0; i < 8; ++i) {
            const long long rowb = rowbase + i * 16;
#pragma unroll
            for (int j = 0; j < 4; ++j) {
                const long long col = colbase + j * 16;
#pragma unroll
                for (int q = 0; q < 4; ++q)
                    Cf[(rowb + q) * (long long)ldc + col] = acc[i][j][q] * rvec[rowb + q];
            }
        }
    }
}

// f32 -> fp16 convert, 4 elems/thread
__global__ __launch_bounds__(256)
void cvt_f16(const float* __restrict__ in, unsigned short* __restrict__ out, long long n4)
{
    const long long i = (long long)blockIdx.x * 256 + threadIdx.x;
    if (i >= n4) return;
    const float4 v = ((const float4*)in)[i];
    h16x4 o;
    o.x = (_Float16)v.x; o.y = (_Float16)v.y;
    o.z = (_Float16)v.z; o.w = (_Float16)v.w;
    ((h16x4*)out)[i] = o;
}

// vt[b][h][n] = v[b*2048+n][h]   (V transpose, bf16)
__global__ __launch_bounds__(256)
void transpose_v(const unsigned short* __restrict__ v, unsigned short* __restrict__ vt)
{
    __shared__ unsigned short t[32][33];
    const int b = blockIdx.z;
    const int n0 = blockIdx.x * 32, h0 = blockIdx.y * 32;
    const int tx = threadIdx.x, ty = threadIdx.y;      // 32 x 8
    const unsigned short* src = v + (long long)b * 2048 * 768;
#pragma unroll
    for (int q = 0; q < 4; ++q)
        t[ty + q * 8][tx] = src[(long long)(n0 + ty + q * 8) * 768 + h0 + tx];
    __syncthreads();
    unsigned short* dst = vt + ((long long)b * 768 + h0) * 2048 + n0;
#pragma unroll
    for (int q = 0; q < 4; ++q)
        dst[(long long)(ty + q * 8) * 2048 + tx] = t[tx][ty + q * 8];
}

// r[row] = 1 / sum(E[row][0:2048])   (E bf16, one 256-thr block per row)
__global__ __launch_bounds__(256)
void rowsum_recip(const unsigned short* __restrict__ E, float* __restrict__ r)
{
    const long long row = blockIdx.x;
    const int t = threadIdx.x, lane = t & 63, w = t >> 6;
    __shared__ float red[4];
    const uint4 v = ((const uint4*)(E + row * 2048))[t];   // 8 bf16
    float s = bf2f((unsigned short)(v.x & 0xffff)) + bf2f((unsigned short)(v.x >> 16))
            + bf2f((unsigned short)(v.y & 0xffff)) + bf2f((unsigned short)(v.y >> 16))
            + bf2f((unsigned short)(v.z & 0xffff)) + bf2f((unsigned short)(v.z >> 16))
            + bf2f((unsigned short)(v.w & 0xffff)) + bf2f((unsigned short)(v.w >> 16));
#pragma unroll
    for (int o = 32; o; o >>= 1) s += __shfl_xor(s, o);
    if (lane == 0) red[w] = s;
    __syncthreads();
    if (t == 0) r[row] = 1.f / ((red[0] + red[1]) + (red[2] + red[3]));
}

extern "C" void kernel_launch(void* const* d_in, const int* in_sizes, int n_in,
                              void* d_out, int out_size, void* d_ws, size_t ws_size,
                              hipStream_t stream)
{
    const float* x    = (const float*)d_in[0];   // [16384, 768]
    const float* W    = (const float*)d_in[1];   // [2304, 768]
    const float* bias = (const float*)d_in[2];   // [2304]
    float* out = (float*)d_out;                  // [8, 2048, 768]

    // ---- workspace layout (bytes), total 196.5 MB
    char* ws = (char*)d_ws;
    unsigned short* xh = (unsigned short*)ws;                      // [16384,768] fp16
    unsigned short* Wh = (unsigned short*)(ws + 25165824LL);       // [2304,768] fp16
    unsigned short* qk = (unsigned short*)(ws + 28704768LL);       // [16384,1536] fp16
    unsigned short* v  = (unsigned short*)(ws + 79036416LL);       // [16384,768] bf16
    unsigned short* vt = (unsigned short*)(ws + 104202240LL);      // [8,768,2048] bf16
    unsigned short* E  = (unsigned short*)(ws + 129368064LL);      // [8,2048,2048] bf16
    float*          r  = (float*)(ws + 196476928LL);               // [16384] f32

    // C1/C2: convert inputs to fp16
    cvt_f16<<<dim3(12288), dim3(256), 0, stream>>>(x, xh, 3145728LL);
    cvt_f16<<<dim3(1728),  dim3(256), 0, stream>>>(W, Wh, 442368LL);

    // K1a: qk = x @ Wqk^T + b  (fp16, M=16384 N=1536 K=768), 2D chunk swizzle
    gemm_mfma<1, true, 2><<<dim3(6, 64, 1), dim3(512), 0, stream>>>(
        xh, Wh, bias, nullptr, nullptr, qk,
        768, 768, 768, 1536, 0, 0, 0, 0);

    // K1b: v = x @ Wv^T + b -> bf16  (M=16384 N=768 K=768), 2D chunk swizzle
    gemm_mfma<2, true, 2><<<dim3(3, 64, 1), dim3(512), 0, stream>>>(
        xh, Wh + 1536LL * 768, bias + 1536, nullptr, nullptr, v,
        768, 768, 768, 768, 0, 0, 0, 0);

    // T: vt = v^T per batch
    transpose_v<<<dim3(64, 24, 8), dim3(32, 8), 0, stream>>>(v, vt);

    // K2: E = exp(q @ k^T)  (fp16, M=2048 N=2048 K=768, z=8), batch-per-XCD
    gemm_mfma<3, true, 1><<<dim3(8, 8, 8), dim3(512), 0, stream>>>(
        qk, qk + 768, nullptr, nullptr, nullptr, E,
        768, 1536, 1536, 2048,
        2048LL * 1536, 2048LL * 1536, 2048LL * 2048, 0);

    // K3': r = 1/rowsum(E)
    rowsum_recip<<<dim3(16384), dim3(256), 0, stream>>>(E, r);

    // K4: out = (E @ vt^T) * r[row]  (bf16, M=2048 N=768 K=2048, z=8), batch-per-XCD
    gemm_mfma<4, false, 1><<<dim3(3, 8, 8), dim3(512), 0, stream>>>(
        E, vt, nullptr, r, out, nullptr,
        2048, 2048, 2048, 768,
        2048LL * 2048, 768LL * 2048, 2048LL * 768, 2048);
}

// Round 7
// 319.376 us; speedup vs baseline: 5.9050x; 1.0562x over previous
//
#include <hip/hip_runtime.h>

// ---------------------------------------------------------------------------
// Attention_4956392259713 — round 14: resubmit of R13 (container infra failure,
// no kernel verdict). R13 = R12 core + 3-buffer counted vmcnt (T4).
// qkv = x@W^T+b; S = q@k^T (unscaled); P = softmax(S); out = P@v
//
// R12 post-mortem: occupancy invariant at 1 block/CU — unified VGPR+AGPR
// (100 arch + 128 acc ≈ 228/wave) caps 2 waves/SIMD regardless of LDS; the
// LDS-halving changed nothing. All structures R7-R12 land at 28-31% MfmaUtil:
// MFMA (~1242 cyc) and LDS (~1536 cyc) windows serialize per K-tile (~3300).
// Untested-clean lever: counted vmcnt (m218 +38%). R12 drains vmcnt(0) for
// loads issued ~700cyc earlier (same iter) -> L2-miss stalls at the barrier
// (Q/K panels 6MB > 4MB L2/XCD). This round: 3-buffer rotation, stage tile
// t+2 at TOP of iter t, end iter with vmcnt(4) (never 0 steady-state):
// drained loads are a FULL iteration (~3300cyc >> 900 HBM) old -> wait ~free,
// 4 loads always in flight across the barrier.
// WAR-safe: buf (t+2)%3 was consumed in iter t-1 (ds_reads drained by lgkm
// waits before that iter's barrier). vmcnt(4) at end of iter t leaves t+2's
// 4 loads in flight, guarantees t+1 resident. Prologue stages t0,t1.
// Hang-audit (R14): uniform control flow at every s_barrier; vmcnt FIFO
// verified (prologue 8->4; steady 8->4; tail 0); cvt grid exact.
// Swizzle (64B rows, verified 0 conflicts): 16B-unit U=u^((row>>1)&3);
// write side = linear gld16 dest + pre-swizzled GLOBAL column (rule #21);
// read side folded into per-lane constant ku.
// Numerics identical (fp16 QKV/QK^T; bf16 E and PV; no max subtraction).
// Fragment maps (m89-verified): A/B idx=lane&15, k=(lane>>4)*8+j;
//                               C/D col=lane&15, row=(lane>>4)*4+reg.
// ---------------------------------------------------------------------------

typedef short    s16x8 __attribute__((ext_vector_type(8)));
typedef _Float16 h16x8 __attribute__((ext_vector_type(8)));
typedef _Float16 h16x4 __attribute__((ext_vector_type(4)));
typedef float    f32x4 __attribute__((ext_vector_type(4)));

__device__ __forceinline__ unsigned short f2bf(float x) {
    unsigned u = __float_as_uint(x);
    u += 0x7fffu + ((u >> 16) & 1u);          // RTNE
    return (unsigned short)(u >> 16);
}
__device__ __forceinline__ float bf2f(unsigned short h) {
    return __uint_as_float(((unsigned)h) << 16);
}
__device__ __forceinline__ unsigned short f2h(float x) {
    _Float16 h = (_Float16)x;                 // v_cvt_f16_f32, RTNE
    unsigned short u;
    __builtin_memcpy(&u, &h, 2);
    return u;
}
__device__ __forceinline__ h16x8 as_h(s16x8 v) {
    h16x8 r; __builtin_memcpy(&r, &v, 16); return r;
}

// async global->LDS, 16 B per lane; LDS dest = wave-uniform base + lane*16
__device__ __forceinline__ void gld16(const void* g, void* l) {
    __builtin_amdgcn_global_load_lds(
        (const __attribute__((address_space(1))) unsigned int*)(unsigned long long)g,
        (__attribute__((address_space(3))) unsigned int*)(unsigned)(unsigned long long)l,
        16, 0, 0);
}

template<bool FP16>
__device__ __forceinline__ f32x4 mma(s16x8 a, s16x8 b, f32x4 c) {
    if constexpr (FP16)
        return __builtin_amdgcn_mfma_f32_16x16x32_f16(as_h(a), as_h(b), c, 0, 0, 0);
    else
        return __builtin_amdgcn_mfma_f32_16x16x32_bf16(a, b, c, 0, 0, 0);
}

// NT GEMM, 512 thr = 8 waves (2Mx4N), tile 256x256, BK=32, 3-buf counted.
// MODE 1: C = acc + bias -> fp16        [K1a]
// MODE 2: C = acc + bias -> bf16        [K1b]
// MODE 3: C = exp(acc)   -> bf16        [K2]
// MODE 4: C = acc * rvec[row] -> f32    [K4]
// SWZ 0: none; 1: 3D batch-per-XCD; 2: 2D row-chunk-per-XCD (gridDim.y%8==0)
template<int MODE, bool FP16, int SWZ>
__global__ __launch_bounds__(512, 2)
void gemm_mfma(const unsigned short* __restrict__ A, const unsigned short* __restrict__ B,
               const float* __restrict__ bias, const float* __restrict__ rvec,
               float* __restrict__ Cf, unsigned short* __restrict__ Ch,
               int K, int lda, int ldb, int ldc,
               long long sA, long long sB, long long sC, long long sR)
{
    __shared__ unsigned short As[3][8192];    // 3 x [256 rows][32 k] 2B, swizzled
    __shared__ unsigned short Bs[3][8192];

    int bx = blockIdx.x, by = blockIdx.y, bz = blockIdx.z;
    if (SWZ == 1) {
        const int l = bx + gridDim.x * (by + gridDim.y * bz);
        bz = l & 7;
        const int t = l >> 3;
        bx = t % gridDim.x;
        by = t / gridDim.x;
    } else if (SWZ == 2) {
        const int l = bx + gridDim.x * by;
        const int c = l & 7;
        const int t = l >> 3;
        const int rows = gridDim.y >> 3;
        bx = t % gridDim.x;
        by = c * rows + t / gridDim.x;
    }

    A += (long long)bz * sA;
    B += (long long)bz * sB;

    const long long m0 = (long long)by * 256;
    const long long n0 = (long long)bx * 256;

    const int tid  = threadIdx.x;
    const int wave = tid >> 6, lane = tid & 63;
    const int wr = wave >> 2, wc = wave & 3;             // 2M x 4N wave grid
    const int ml = lane & 15;                            // fragment row-in-16
    // swizzled k-unit for fragment reads: U = u ^ ((row>>1)&3); row bases are
    // multiples of 16 so (row>>1)&3 == (ml>>1)&3 -> per-lane constant.
    const int ku = (((lane >> 4) ^ ((ml >> 1) & 3)) * 8);
    const int srr = wave * 16 + (lane >> 2);             // staging row 0..127
    // pre-swizzled GLOBAL column: slot (r,U) holds global unit u = U^((r>>1)&3),
    // with r = wave*16 + (lane>>2) -> (r>>1)&3 == (lane>>3)&3.
    const int skc = (((lane & 3) ^ ((lane >> 3) & 3)) * 8);

    const int aidx = (wr * 128 + ml) * 32 + ku;          // LDS elem index
    const int bidx = (wc * 64  + ml) * 32 + ku;

    const unsigned short* Abase = A + (m0 + srr) * (long long)lda + skc;
    const unsigned short* Bbase = B + (n0 + srr) * (long long)ldb + skc;
    const long long a128 = 128LL * lda, b128 = 128LL * ldb;

    // stage one 256x32 operand tile: 2 x (512 thr x 16B) = 16KB
    auto stage_a = [&](int t, int buf) {
        const unsigned short* p = Abase + t * 32;
        gld16(p,        &As[buf][wave * 512]);
        gld16(p + a128, &As[buf][4096 + wave * 512]);
    };
    auto stage_b = [&](int t, int buf) {
        const unsigned short* p = Bbase + t * 32;
        gld16(p,        &Bs[buf][wave * 512]);
        gld16(p + b128, &Bs[buf][4096 + wave * 512]);
    };

    f32x4 acc[8][4];
#pragma unroll
    for (int i = 0; i < 8; ++i)
#pragma unroll
        for (int j = 0; j < 4; ++j) acc[i][j] = f32x4{0.f, 0.f, 0.f, 0.f};

    const int nt = K >> 5;                    // K-tiles of 32 (>= 24 here)

    // prologue: stage tiles 0,1 (depth 2); tile0 ready at vmcnt(4)
    stage_a(0, 0); stage_b(0, 0);
    stage_a(1, 1); stage_b(1, 1);
    asm volatile("s_waitcnt vmcnt(4)" ::: "memory");
    __builtin_amdgcn_s_barrier();
    __builtin_amdgcn_sched_barrier(0);

    int cur = 0;
    for (int t = 0; t < nt; ++t) {
        const unsigned short* as = &As[cur][0];
        const unsigned short* bs = &Bs[cur][0];
        const bool pf2 = (t + 2 < nt);

        // stage tile t+2 into the buffer consumed in iter t-1 (WAR-safe)
        if (pf2) {
            const int nb = (cur >= 1) ? cur - 1 : 2;     // (t+2)%3
            stage_a(t + 2, nb); stage_b(t + 2, nb);
        }

        s16x8 a8[8], b4[4];
        // issue all 12 ds_reads; compiler emits granular lgkm waits so the
        // MFMA cluster below overlaps the tail reads.
#pragma unroll
        for (int i = 0; i < 4; ++i) a8[i] = *(const s16x8*)&as[aidx + i * 512];
#pragma unroll
        for (int j = 0; j < 4; ++j) b4[j] = *(const s16x8*)&bs[bidx + j * 512];
#pragma unroll
        for (int i = 0; i < 4; ++i) a8[4 + i] = *(const s16x8*)&as[aidx + (i + 4) * 512];

        __builtin_amdgcn_s_setprio(1);
#pragma unroll
        for (int i = 0; i < 8; ++i)
#pragma unroll
            for (int j = 0; j < 4; ++j)
                acc[i][j] = mma<FP16>(a8[i], b4[j], acc[i][j]);
        __builtin_amdgcn_s_setprio(0);

        // counted drain: tile t+1 (issued a full iter ago) resident; tile
        // t+2's 4 loads stay in flight across the barrier (T4: never 0).
        if (pf2)               { asm volatile("s_waitcnt vmcnt(4)" ::: "memory"); }
        else if (t + 1 < nt)   { asm volatile("s_waitcnt vmcnt(0)" ::: "memory"); }
        __builtin_amdgcn_s_barrier();
        __builtin_amdgcn_sched_barrier(0);
        cur = (cur == 2) ? 0 : cur + 1;
    }

    // ---- epilogue: C/D map col=lane&15, row=(lane>>4)*4+reg
    const int r0 = (lane >> 4) * 4;
    const long long rowbase = m0 + wr * 128 + r0;
    const long long colbase = n0 + wc * 64 + ml;
    if (MODE == 1 || MODE == 2) {
#pragma unroll
        for (int i = 0; i < 8; ++i) {
            const long long rowb = rowbase + i * 16;
#pragma unroll
            for (int j = 0; j < 4; ++j) {
                const long long col = colbase + j * 16;
                const float bj = bias[col];
#pragma unroll
                for (int q = 0; q < 4; ++q) {
                    const float vv = acc[i][j][q] + bj;
                    Ch[(rowb + q) * (long long)ldc + col] = (MODE == 1) ? f2h(vv) : f2bf(vv);
                }
            }
        }
    } else if (MODE == 3) {
        Ch += (long long)bz * sC;
#pragma unroll
        for (int i = 0; i < 8; ++i) {
            const long long rowb = rowbase + i * 16;
#pragma unroll
            for (int j = 0; j < 4; ++j) {
                const long long col = colbase + j * 16;
#pragma unroll
                for (int q = 0; q < 4; ++q)
                    Ch[(rowb + q) * (long long)ldc + col] = f2bf(__expf(acc[i][j][q]));
            }
        }
    } else {   // MODE 4
        Cf += (long long)bz * sC;
        rvec += (long long)bz * sR;
#pragma unroll
        for (int i = 0; i < 8; ++i) {
            const long long rowb = rowbase + i * 16;
#pragma unroll
            for (int j = 0; j < 4; ++j) {
                const long long col = colbase + j * 16;
#pragma unroll
                for (int q = 0; q < 4; ++q)
                    Cf[(rowb + q) * (long long)ldc + col] = acc[i][j][q] * rvec[rowb + q];
            }
        }
    }
}

// f32 -> fp16 convert, 4 elems/thread, two source buffers in one launch
__global__ __launch_bounds__(256)
void cvt_f16_2(const float* __restrict__ a, long long na4,
               const float* __restrict__ b, long long nb4,
               unsigned short* __restrict__ oa, unsigned short* __restrict__ ob)
{
    const long long i = (long long)blockIdx.x * 256 + threadIdx.x;
    const float4* src;
    h16x4* dst;
    long long idx;
    if (i < na4)            { src = (const float4*)a; dst = (h16x4*)oa; idx = i; }
    else if (i < na4 + nb4) { src = (const float4*)b; dst = (h16x4*)ob; idx = i - na4; }
    else return;
    const float4 v = src[idx];
    h16x4 o;
    o.x = (_Float16)v.x; o.y = (_Float16)v.y;
    o.z = (_Float16)v.z; o.w = (_Float16)v.w;
    dst[idx] = o;
}

// vt[b][h][n] = v[b*2048+n][h]   (V transpose, bf16)
__global__ __launch_bounds__(256)
void transpose_v(const unsigned short* __restrict__ v, unsigned short* __restrict__ vt)
{
    __shared__ unsigned short t[32][33];
    const int b = blockIdx.z;
    const int n0 = blockIdx.x * 32, h0 = blockIdx.y * 32;
    const int tx = threadIdx.x, ty = threadIdx.y;      // 32 x 8
    const unsigned short* src = v + (long long)b * 2048 * 768;
#pragma unroll
    for (int q = 0; q < 4; ++q)
        t[ty + q * 8][tx] = src[(long long)(n0 + ty + q * 8) * 768 + h0 + tx];
    __syncthreads();
    unsigned short* dst = vt + ((long long)b * 768 + h0) * 2048 + n0;
#pragma unroll
    for (int q = 0; q < 4; ++q)
        dst[(long long)(ty + q * 8) * 2048 + tx] = t[tx][ty + q * 8];
}

// r[row] = 1 / sum(E[row][0:2048])   (E bf16, one 256-thr block per row)
__global__ __launch_bounds__(256)
void rowsum_recip(const unsigned short* __restrict__ E, float* __restrict__ r)
{
    const long long row = blockIdx.x;
    const int t = threadIdx.x, lane = t & 63, w = t >> 6;
    __shared__ float red[4];
    const uint4 v = ((const uint4*)(E + row * 2048))[t];   // 8 bf16
    float s = bf2f((unsigned short)(v.x & 0xffff)) + bf2f((unsigned short)(v.x >> 16))
            + bf2f((unsigned short)(v.y & 0xffff)) + bf2f((unsigned short)(v.y >> 16))
            + bf2f((unsigned short)(v.z & 0xffff)) + bf2f((unsigned short)(v.z >> 16))
            + bf2f((unsigned short)(v.w & 0xffff)) + bf2f((unsigned short)(v.w >> 16));
#pragma unroll
    for (int o = 32; o; o >>= 1) s += __shfl_xor(s, o);
    if (lane == 0) red[w] = s;
    __syncthreads();
    if (t == 0) r[row] = 1.f / ((red[0] + red[1]) + (red[2] + red[3]));
}

extern "C" void kernel_launch(void* const* d_in, const int* in_sizes, int n_in,
                              void* d_out, int out_size, void* d_ws, size_t ws_size,
                              hipStream_t stream)
{
    const float* x    = (const float*)d_in[0];   // [16384, 768]
    const float* W    = (const float*)d_in[1];   // [2304, 768]
    const float* bias = (const float*)d_in[2];   // [2304]
    float* out = (float*)d_out;                  // [8, 2048, 768]

    // ---- workspace layout (bytes), total 196.5 MB
    char* ws = (char*)d_ws;
    unsigned short* xh = (unsigned short*)ws;                      // [16384,768] fp16
    unsigned short* Wh = (unsigned short*)(ws + 25165824LL);       // [2304,768] fp16
    unsigned short* qk = (unsigned short*)(ws + 28704768LL);       // [16384,1536] fp16
    unsigned short* v  = (unsigned short*)(ws + 79036416LL);       // [16384,768] bf16
    unsigned short* vt = (unsigned short*)(ws + 104202240LL);      // [8,768,2048] bf16
    unsigned short* E  = (unsigned short*)(ws + 129368064LL);      // [8,2048,2048] bf16
    float*          r  = (float*)(ws + 196476928LL);               // [16384] f32

    // C1+C2: convert x and W to fp16 in one launch
    cvt_f16_2<<<dim3(14016), dim3(256), 0, stream>>>(
        x, 3145728LL, W, 442368LL, xh, Wh);

    // K1a: qk = x @ Wqk^T + b  (fp16, M=16384 N=1536 K=768), 2D chunk swizzle
    gemm_mfma<1, true, 2><<<dim3(6, 64, 1), dim3(512), 0, stream>>>(
        xh, Wh, bias, nullptr, nullptr, qk,
        768, 768, 768, 1536, 0, 0, 0, 0);

    // K1b: v = x @ Wv^T + b -> bf16  (M=16384 N=768 K=768), 2D chunk swizzle
    gemm_mfma<2, true, 2><<<dim3(3, 64, 1), dim3(512), 0, stream>>>(
        xh, Wh + 1536LL * 768, bias + 1536, nullptr, nullptr, v,
        768, 768, 768, 768, 0, 0, 0, 0);

    // T: vt = v^T per batch
    transpose_v<<<dim3(64, 24, 8), dim3(32, 8), 0, stream>>>(v, vt);

    // K2: E = exp(q @ k^T)  (fp16, M=2048 N=2048 K=768, z=8), batch-per-XCD
    gemm_mfma<3, true, 1><<<dim3(8, 8, 8), dim3(512), 0, stream>>>(
        qk, qk + 768, nullptr, nullptr, nullptr, E,
        768, 1536, 1536, 2048,
        2048LL * 1536, 2048LL * 1536, 2048LL * 2048, 0);

    // K3': r = 1/rowsum(E)
    rowsum_recip<<<dim3(16384), dim3(256), 0, stream>>>(E, r);

    // K4: out = (E @ vt^T) * r[row]  (bf16, M=2048 N=768 K=2048, z=8), batch-per-XCD
    gemm_mfma<4, false, 1><<<dim3(3, 8, 8), dim3(512), 0, stream>>>(
        E, vt, nullptr, r, out, nullptr,
        2048, 2048, 2048, 768,
        2048LL * 2048, 768LL * 2048, 2048LL * 768, 2048);
}